// Round 5
// baseline (547.380 us; speedup 1.0000x reference)
//
#include <hip/hip_runtime.h>
#include <hip/hip_bf16.h>
#include <math.h>
#include <stdint.h>

#define DMODEL 1024
#define DSTATE 16
#define DINNER 2048
#define DTRANK 64
#define NB 2
#define LSEQ 1024
#define ROWS (NB*LSEQ)   // 2048
#define NCH 32           // chunks per sequence
#define LCH (LSEQ/NCH)   // 32 steps per chunk
#define KSPLIT 8         // x_proj split-K factor

typedef __bf16 bf16_t;
typedef __bf16 bf16x8 __attribute__((ext_vector_type(8)));
typedef __bf16 bf16x4 __attribute__((ext_vector_type(4)));
typedef float  f32x4  __attribute__((ext_vector_type(4)));

#define AS1(p) ((const __attribute__((address_space(1))) void*)(p))
#define AS3(p) ((__attribute__((address_space(3))) void*)(uint32_t)(uintptr_t)(p))

static __device__ __forceinline__ float sigmoidf_(float x){ return 1.f/(1.f+__expf(-x)); }
static __device__ __forceinline__ float softplusf_(float x){ return fmaxf(x,0.f) + log1pf(__expf(-fabsf(x))); }

// ---------------- f32 -> bf16 conversion (weights) ----------------
__global__ __launch_bounds__(256) void cvt_kernel(const float* __restrict__ in,
    bf16_t* __restrict__ out, int n4)
{
  int i = blockIdx.x*256 + threadIdx.x;
  if (i < n4){
    float4 v = ((const float4*)in)[i];
    bf16x4 o = { (bf16_t)v.x, (bf16_t)v.y, (bf16_t)v.z, (bf16_t)v.w };
    ((bf16x4*)out)[i] = o;
  }
}

// ---------------- LayerNorm over last dim (1024), one block per row ----------------
template<int OUTBF>
__global__ __launch_bounds__(256) void ln_kernel(const float* __restrict__ x,
    const float* __restrict__ g, const float* __restrict__ b,
    float* __restrict__ outf, bf16_t* __restrict__ outb)
{
  int row = blockIdx.x;
  float4 v = ((const float4*)(x + (size_t)row*DMODEL))[threadIdx.x];
  float s  = v.x+v.y+v.z+v.w;
  float s2 = v.x*v.x+v.y*v.y+v.z*v.z+v.w*v.w;
  #pragma unroll
  for (int off=32; off>=1; off>>=1){ s += __shfl_xor(s,off); s2 += __shfl_xor(s2,off); }
  __shared__ float red[8];
  int lane = threadIdx.x & 63, wid = threadIdx.x >> 6;
  if (lane==0){ red[wid]=s; red[4+wid]=s2; }
  __syncthreads();
  float ts  = red[0]+red[1]+red[2]+red[3];
  float ts2 = red[4]+red[5]+red[6]+red[7];
  float mean = ts*(1.f/DMODEL);
  float var  = ts2*(1.f/DMODEL) - mean*mean;
  float rstd = rsqrtf(var + 1e-5f);
  float4 gv = ((const float4*)g)[threadIdx.x];
  float4 bv = ((const float4*)b)[threadIdx.x];
  float4 o;
  o.x=(v.x-mean)*rstd*gv.x+bv.x;
  o.y=(v.y-mean)*rstd*gv.y+bv.y;
  o.z=(v.z-mean)*rstd*gv.z+bv.z;
  o.w=(v.w-mean)*rstd*gv.w+bv.w;
  if (OUTBF){
    bf16x4 ob = { (bf16_t)o.x, (bf16_t)o.y, (bf16_t)o.z, (bf16_t)o.w };
    ((bf16x4*)(outb + (size_t)row*DMODEL))[threadIdx.x] = ob;
  } else {
    ((float4*)(outf + (size_t)row*DMODEL))[threadIdx.x] = o;
  }
}

// ================= bf16 MFMA GEMM: C[M,N] = A[M,K] * W[N,K]^T =================
// 128x128 tile, BK=64, 4 waves (2x2), each wave 64x64 = 4x4 frags of 16x16x32.
// EPI: 1 = softplus(acc+bias[n]) fp32; 2 = acc+addsrc fp32;
//      4 = bf16 C2 via LDS-staged coalesced store; 5 = fp32 split-K partial
// SWZ: XCD-rectangle block swizzle (requires total blocks %8==0)
#define GBM 128
#define GBN 128
#define GBK 64

template<int EPI, bool NGUARD, bool SWZ>
__global__ __launch_bounds__(256) void gemm_bf16(
    const bf16_t* __restrict__ A, int lda,
    const bf16_t* __restrict__ W, int ldw,
    float* __restrict__ C, int ldc,
    int M, int N, int K,
    const float* __restrict__ bias,
    const float* __restrict__ addsrc,
    bf16_t* __restrict__ C2)
{
  __shared__ __align__(16) char lds[2*GBM*GBK*2];   // 32 KB: sA | sB
  char* sA = lds;
  char* sB = lds + GBM*GBK*2;
  const int tid  = threadIdx.x;
  const int lane = tid & 63, wid = tid >> 6;
  const int wr = wid >> 1, wc = wid & 1;            // 2x2 wave grid
  const int frow = lane & 15, kgrp = lane >> 4;

  int bx = blockIdx.x, by = blockIdx.y;
  if (SWZ) {
    int gx = gridDim.x, gy = gridDim.y;
    int bid = by*gx + bx;
    int q = (gx*gy) >> 3;
    int nid = (bid & 7)*q + (bid >> 3);
    int stripH = gy << 3;
    int strip = nid / stripH;
    int rem   = nid % stripH;
    bx = (strip << 3) + (rem & 7);
    by = rem >> 3;
  }
  const int m0 = by*GBM, n0 = bx*GBN;
  const int srow  = (lane >> 3);          // 0..7 row within chunk
  const int scolb = (lane & 7) * 16;      // byte offset in K (0..112)

  f32x4 acc[4][4];
  #pragma unroll
  for (int i=0;i<4;i++)
    #pragma unroll
    for (int j=0;j<4;j++)
      acc[i][j] = (f32x4){0.f,0.f,0.f,0.f};

  const int ksl = K / gridDim.z;
  const int kb  = blockIdx.z * ksl;
  for (int k0 = kb; k0 < kb + ksl; k0 += GBK) {
    #pragma unroll
    for (int r=0;r<4;++r){
      int ci  = r*4 + wid;                // 0..15
      int row = ci*8 + srow;              // 0..127
      {
        const char* src = (const char*)A + ((size_t)(m0+row)*lda + k0)*2 + scolb;
        __builtin_amdgcn_global_load_lds(AS1(src), AS3(sA + ci*1024), 16, 0, 0);
      }
      {
        int grow = n0 + row;
        if (NGUARD) grow = (grow < N) ? grow : (N-1);
        const char* src = (const char*)W + ((size_t)grow*ldw + k0)*2 + scolb;
        __builtin_amdgcn_global_load_lds(AS1(src), AS3(sB + ci*1024), 16, 0, 0);
      }
    }
    __syncthreads();
    #pragma unroll
    for (int ks=0; ks<2; ++ks){
      bf16x8 af[4], bfr[4];
      #pragma unroll
      for (int i=0;i<4;i++)
        af[i] = *(const bf16x8*)(sA + (wr*64 + i*16 + frow)*128 + ks*64 + kgrp*16);
      #pragma unroll
      for (int j=0;j<4;j++)
        bfr[j] = *(const bf16x8*)(sB + (wc*64 + j*16 + frow)*128 + ks*64 + kgrp*16);
      #pragma unroll
      for (int i=0;i<4;i++)
        #pragma unroll
        for (int j=0;j<4;j++)
          acc[i][j] = __builtin_amdgcn_mfma_f32_16x16x32_bf16(af[i], bfr[j], acc[i][j], 0, 0, 0);
    }
    __syncthreads();
  }

  if (EPI==4) {
    // stage C tile to LDS as bf16 (XOR-swizzled), then coalesced 16B stores
    #pragma unroll
    for (int i=0;i<4;i++){
      int rbase = wr*64 + i*16 + kgrp*4;
      #pragma unroll
      for (int j=0;j<4;j++){
        int col = wc*64 + j*16 + frow;
        #pragma unroll
        for (int q=0;q<4;q++){
          int row = rbase + q;
          int byte = (row<<8) + (col<<1);
          byte ^= (row & 7) << 4;
          *(bf16_t*)(lds + byte) = (bf16_t)acc[i][j][q];
        }
      }
    }
    __syncthreads();
    // each thread: one half-row (128 B) -> 8 x 16B stores; 256 threads cover 32 KB
    int r = tid >> 1;
    int hb = (tid & 1) << 7;              // byte offset 0/128 within row
    size_t gbase = (size_t)(m0 + r)*ldc + n0 + ((tid & 1) << 6);
    #pragma unroll
    for (int i=0;i<8;i++){
      int byte = (r<<8) + hb + (i<<4);
      byte ^= (r & 7) << 4;
      bf16x8 v = *(const bf16x8*)(lds + byte);
      *(bf16x8*)(C2 + gbase + (i<<3)) = v;
    }
    return;
  }

  float* Cw = (EPI==5) ? (C + (size_t)blockIdx.z*(size_t)M*ldc) : C;
  #pragma unroll
  for (int i=0;i<4;i++){
    int rbase = m0 + wr*64 + i*16 + kgrp*4;
    #pragma unroll
    for (int j=0;j<4;j++){
      int col = n0 + wc*64 + j*16 + frow;
      if (NGUARD && col >= N) continue;
      #pragma unroll
      for (int q=0;q<4;q++){
        float v = acc[i][j][q];
        int row = rbase + q;
        if (EPI==1) v = softplusf_(v + bias[col]);
        if (EPI==2) v += addsrc[(size_t)row*ldc + col];
        Cw[(size_t)row*ldc + col] = v;
      }
    }
  }
}

// ---------- x_proj split-K reduce: xdbl = sum of partials; dual fp32/bf16 ----------
__global__ __launch_bounds__(256) void xp_reduce(
    const float* __restrict__ part, float* __restrict__ xdbl, bf16_t* __restrict__ xdbl_b)
{
  int idx = blockIdx.x*256 + threadIdx.x;     // ROWS*96
  float s = 0.f;
  #pragma unroll
  for (int k=0;k<KSPLIT;k++) s += part[(size_t)k*ROWS*96 + idx];
  xdbl[idx] = s;
  xdbl_b[idx] = (bf16_t)s;
}

// ---------- causal depthwise conv (width 4) + bias + SiLU; bf16 in/out ----------
__global__ __launch_bounds__(256) void conv_silu_kernel(
    const bf16_t* __restrict__ xzb, const float* __restrict__ cw,
    const float* __restrict__ cb, bf16_t* __restrict__ ub)
{
  int idx = blockIdx.x*256 + threadIdx.x;     // B*L*DINNER threads
  int d  = idx & (DINNER-1);
  int bl = idx >> 11;
  int l  = bl & (LSEQ-1);
  const bf16_t* col = xzb + (size_t)bl*(2*DINNER) + d;
  float w0=cw[d*4+0], w1=cw[d*4+1], w2=cw[d*4+2], w3=cw[d*4+3];
  float x3 = (float)col[0];
  float x2 = (l>=1) ? (float)col[-(ptrdiff_t)(2*DINNER)]  : 0.f;
  float x1 = (l>=2) ? (float)col[-(ptrdiff_t)(4*DINNER)]  : 0.f;
  float x0 = (l>=3) ? (float)col[-(ptrdiff_t)(6*DINNER)]  : 0.f;
  float acc = cb[d] + w0*x0 + w1*x1 + w2*x2 + w3*x3;
  float uu = acc * sigmoidf_(acc);
  ub[(size_t)bl*DINNER + d] = (bf16_t)uu;
}

// ======================= chunked selective scan =======================
__global__ __launch_bounds__(256) void scan_phase1(
    const float* __restrict__ delta, const bf16_t* __restrict__ u,
    const float* __restrict__ xdbl, const float* __restrict__ A_log,
    float* __restrict__ hout, float* __restrict__ sumd)
{
  int gid = blockIdx.x*256 + threadIdx.x;     // B*NCH*DINNER = 131072
  int d = gid & (DINNER-1);
  int c = (gid >> 11) & (NCH-1);
  int b = gid >> 16;
  float A[DSTATE];
  #pragma unroll
  for (int s=0;s<DSTATE;s++) A[s] = -__expf(A_log[d*DSTATE+s]);
  int l0 = c*LCH;
  const float*  drow = delta + ((size_t)(b*LSEQ + l0))*DINNER + d;
  const bf16_t* urow = u     + ((size_t)(b*LSEQ + l0))*DINNER + d;
  const float*  xrow = xdbl  + ((size_t)(b*LSEQ + l0))*96 + DTRANK;   // B at [0..15]
  float h[DSTATE] = {};
  float sd = 0.f;
  for (int l=0; l<LCH; ++l) {
    float dv = drow[(size_t)l*DINNER];
    float uv = (float)urow[(size_t)l*DINNER];
    const float* bc = xrow + l*96;
    float du = dv*uv;
    sd += dv;
    #pragma unroll
    for (int s=0;s<DSTATE;s++)
      h[s] = __expf(dv*A[s])*h[s] + du*bc[s];
  }
  float* hp = hout + (((size_t)(b*NCH + c))*DINNER + d)*DSTATE;
  #pragma unroll
  for (int q=0;q<4;q++)
    ((float4*)hp)[q] = make_float4(h[4*q],h[4*q+1],h[4*q+2],h[4*q+3]);
  sumd[((size_t)(b*NCH + c))*DINNER + d] = sd;
}

__global__ __launch_bounds__(256) void scan_phase2(
    float* __restrict__ hout, const float* __restrict__ sumd,
    const float* __restrict__ A_log)
{
  int gid = blockIdx.x*256 + threadIdx.x;     // B*DINNER*DSTATE = 65536
  int s = gid & (DSTATE-1);
  int d = (gid >> 4) & (DINNER-1);
  int b = gid >> 15;
  float A = -__expf(A_log[d*DSTATE+s]);
  float h = 0.f;
  for (int c=0; c<NCH; ++c) {
    size_t hi = (((size_t)(b*NCH + c))*DINNER + d)*DSTATE + s;
    float tmp = hout[hi];
    hout[hi] = h;                              // hin for chunk c
    float P = __expf(A * sumd[((size_t)(b*NCH + c))*DINNER + d]);
    h = P*h + tmp;
  }
}

// Phase 3: rescan with hin; fused epilogue; ys (bf16) overwrites u in place.
// NOTE: ysb and u intentionally alias (per-thread same-address read-then-write)
// -> no __restrict__ on either.
__global__ __launch_bounds__(256) void scan_phase3(
    const float* __restrict__ delta, bf16_t* ysb,
    const bf16_t* u,
    const bf16_t* __restrict__ xzb,   // res at [row][2048+d], stride 4096
    const float* __restrict__ xdbl,   // [row][96]
    const float* __restrict__ A_log,
    const float* __restrict__ Dp,
    const float* __restrict__ hin)
{
  int gid = blockIdx.x*256 + threadIdx.x;     // B*NCH*DINNER
  int d = gid & (DINNER-1);
  int c = (gid >> 11) & (NCH-1);
  int b = gid >> 16;
  float A[DSTATE];
  #pragma unroll
  for (int s=0;s<DSTATE;s++) A[s] = -__expf(A_log[d*DSTATE+s]);
  float Dpd = Dp[d];
  float h[DSTATE];
  const float* hp = hin + (((size_t)(b*NCH + c))*DINNER + d)*DSTATE;
  #pragma unroll
  for (int q=0;q<4;q++){
    float4 hv = ((const float4*)hp)[q];
    h[4*q]=hv.x; h[4*q+1]=hv.y; h[4*q+2]=hv.z; h[4*q+3]=hv.w;
  }
  int l0 = c*LCH;
  const float*  drow = delta + ((size_t)(b*LSEQ + l0))*DINNER + d;
  const bf16_t* urow = u     + ((size_t)(b*LSEQ + l0))*DINNER + d;
  const bf16_t* rrow = xzb   + ((size_t)(b*LSEQ + l0))*2*DINNER + DINNER + d;
  const float*  xrow = xdbl  + ((size_t)(b*LSEQ + l0))*96 + DTRANK;
  bf16_t* yrow = ysb + ((size_t)(b*LSEQ + l0))*DINNER + d;
  for (int l=0; l<LCH; ++l) {
    float dv = drow[(size_t)l*DINNER];
    float uv = (float)urow[(size_t)l*DINNER];
    float rv = (float)rrow[(size_t)l*2*DINNER];
    const float* bc = xrow + l*96;            // B at [0..15], C at [16..31]
    float du = dv*uv;
    float y = 0.f;
    #pragma unroll
    for (int s=0;s<DSTATE;s++){
      float dA = __expf(dv*A[s]);
      h[s] = dA*h[s] + du*bc[s];
      y += h[s]*bc[DSTATE+s];
    }
    y = (y + uv*Dpd) * (rv * sigmoidf_(rv));
    yrow[(size_t)l*DINNER] = (bf16_t)y;
  }
}

extern "C" void kernel_launch(void* const* d_in, const int* in_sizes, int n_in,
                              void* d_out, int out_size, void* d_ws, size_t ws_size,
                              hipStream_t stream)
{
  const float* x      = (const float*)d_in[0];
  const float* ln_g   = (const float*)d_in[1];
  const float* ln_b   = (const float*)d_in[2];
  const float* in_w   = (const float*)d_in[3];
  const float* conv_w = (const float*)d_in[4];
  const float* conv_b = (const float*)d_in[5];
  const float* xp_w   = (const float*)d_in[6];
  const float* dt_w   = (const float*)d_in[7];
  const float* dt_b   = (const float*)d_in[8];
  const float* A_log  = (const float*)d_in[9];
  const float* Dp     = (const float*)d_in[10];
  const float* out_w  = (const float*)d_in[11];
  const float* fn_g   = (const float*)d_in[12];
  const float* fn_b   = (const float*)d_in[13];
  float* out = (float*)d_out;

  char* p = (char*)d_ws;
  auto alloc = [&](size_t bytes)->char*{ char* r = p; p += (bytes + 255) & ~(size_t)255; return r; };

  const size_t N_INW = (size_t)2*2*DINNER*DMODEL;
  const size_t N_XPW = (size_t)2*96*DINNER;
  const size_t N_DTW = (size_t)2*DINNER*DTRANK;
  const size_t N_OUTW= (size_t)2*DMODEL*DINNER;

  bf16_t* inw_b  = (bf16_t*)alloc(N_INW*2);
  bf16_t* xpw_b  = (bf16_t*)alloc(N_XPW*2);
  bf16_t* dtw_b  = (bf16_t*)alloc(N_DTW*2);
  bf16_t* outw_b = (bf16_t*)alloc(N_OUTW*2);
  float*  x_cur  = (float*) alloc((size_t)ROWS*DMODEL*4);
  bf16_t* xn_b   = (bf16_t*)alloc((size_t)ROWS*DMODEL*2);
  bf16_t* xzb    = (bf16_t*)alloc((size_t)ROWS*2*DINNER*2);   // 16 MB bf16
  bf16_t* ub_b   = (bf16_t*)alloc((size_t)ROWS*DINNER*2);     // u, later ys
  float*  xdbl   = (float*) alloc((size_t)ROWS*96*4);
  bf16_t* xdbl_b = (bf16_t*)alloc((size_t)ROWS*96*2);
  float*  xpart  = (float*) alloc((size_t)KSPLIT*ROWS*96*4);  // 6.3 MB
  float*  delta  = (float*) alloc((size_t)ROWS*DINNER*4);
  float*  hout   = (float*) alloc((size_t)NB*NCH*DINNER*DSTATE*4); // 8 MB
  float*  sumd   = (float*) alloc((size_t)NB*NCH*DINNER*4);
  bf16_t* ys_b   = ub_b;   // phase3 overwrites u in place (element-wise safe)

  cvt_kernel<<<(int)((N_INW/4 +255)/256),256,0,stream>>>(in_w,  inw_b,  (int)(N_INW/4));
  cvt_kernel<<<(int)((N_XPW/4 +255)/256),256,0,stream>>>(xp_w,  xpw_b,  (int)(N_XPW/4));
  cvt_kernel<<<(int)((N_DTW/4 +255)/256),256,0,stream>>>(dt_w,  dtw_b,  (int)(N_DTW/4));
  cvt_kernel<<<(int)((N_OUTW/4+255)/256),256,0,stream>>>(out_w, outw_b, (int)(N_OUTW/4));

  for (int layer=0; layer<2; ++layer) {
    const float* xin = (layer==0) ? x : x_cur;
    const float* Al  = A_log + (size_t)layer*DINNER*DSTATE;
    ln_kernel<1><<<ROWS,256,0,stream>>>(xin, ln_g+layer*DMODEL, ln_b+layer*DMODEL, nullptr, xn_b);
    // xz = xn @ in_w^T   [2048 x 4096], K=1024  -> bf16 out via LDS epilogue
    gemm_bf16<4,false,true><<<dim3(2*DINNER/GBN, ROWS/GBM),256,0,stream>>>(
        xn_b, DMODEL, inw_b + (size_t)layer*2*DINNER*DMODEL, DMODEL,
        nullptr, 2*DINNER, ROWS, 2*DINNER, DMODEL, nullptr, nullptr, xzb);
    // u = silu(conv(xz[:, :2048]) + cb)  (bf16)
    conv_silu_kernel<<<(ROWS*DINNER)/256,256,0,stream>>>(
        xzb, conv_w + (size_t)layer*DINNER*4, conv_b + (size_t)layer*DINNER, ub_b);
    // xdbl = u @ xp_w^T   [2048 x 96], K=2048, split-K=8 partials + reduce
    gemm_bf16<5,true,false><<<dim3(1, ROWS/GBM, KSPLIT),256,0,stream>>>(
        ub_b, DINNER, xpw_b + (size_t)layer*96*DINNER, DINNER,
        xpart, 96, ROWS, 96, DINNER, nullptr, nullptr, nullptr);
    xp_reduce<<<(ROWS*96)/256,256,0,stream>>>(xpart, xdbl, xdbl_b);
    // delta = softplus(xdbl[:, :64] @ dt_w^T + dt_b)   [2048 x 2048], K=64
    gemm_bf16<1,false,true><<<dim3(DINNER/GBN, ROWS/GBM),256,0,stream>>>(
        xdbl_b, 96, dtw_b + (size_t)layer*DINNER*DTRANK, DTRANK,
        delta, DINNER, ROWS, DINNER, DTRANK,
        dt_b + (size_t)layer*DINNER, nullptr, nullptr);
    // chunked selective scan (ys bf16, in place over u)
    scan_phase1<<<(NB*NCH*DINNER)/256,256,0,stream>>>(delta, ub_b, xdbl, Al, hout, sumd);
    scan_phase2<<<(NB*DINNER*DSTATE)/256,256,0,stream>>>(hout, sumd, Al);
    scan_phase3<<<(NB*NCH*DINNER)/256,256,0,stream>>>(
        delta, ys_b, ub_b, xzb, xdbl, Al, Dp + (size_t)layer*DINNER, hout);
    // x_cur = xin + ys @ out_w^T   [2048 x 1024], K=2048
    gemm_bf16<2,false,true><<<dim3(DMODEL/GBN, ROWS/GBM),256,0,stream>>>(
        ys_b, DINNER, outw_b + (size_t)layer*DMODEL*DINNER, DINNER,
        x_cur, DMODEL, ROWS, DMODEL, DINNER, nullptr, xin, nullptr);
  }
  ln_kernel<0><<<ROWS,256,0,stream>>>(x_cur, fn_g, fn_b, out, nullptr);
}

// Round 7
// 480.205 us; speedup vs baseline: 1.1399x; 1.1399x over previous
//
#include <hip/hip_runtime.h>
#include <hip/hip_bf16.h>
#include <math.h>
#include <stdint.h>

#define DMODEL 1024
#define DSTATE 16
#define DINNER 2048
#define DTRANK 64
#define NB 2
#define LSEQ 1024
#define ROWS (NB*LSEQ)   // 2048
#define NCH 64           // chunks per sequence
#define LCH (LSEQ/NCH)   // 16 steps per chunk
#define KSPLIT 8         // x_proj split-K factor

typedef __bf16 bf16_t;
typedef __bf16 bf16x8 __attribute__((ext_vector_type(8)));
typedef __bf16 bf16x4 __attribute__((ext_vector_type(4)));
typedef float  f32x4  __attribute__((ext_vector_type(4)));

#define AS1(p) ((const __attribute__((address_space(1))) void*)(p))
#define AS3(p) ((__attribute__((address_space(3))) void*)(uint32_t)(uintptr_t)(p))

static __device__ __forceinline__ float sigmoidf_(float x){ return 1.f/(1.f+__expf(-x)); }
static __device__ __forceinline__ float softplusf_(float x){ return fmaxf(x,0.f) + log1pf(__expf(-fabsf(x))); }

// ---------------- f32 -> bf16 conversion (weights) ----------------
__global__ __launch_bounds__(256) void cvt_kernel(const float* __restrict__ in,
    bf16_t* __restrict__ out, int n4)
{
  int i = blockIdx.x*256 + threadIdx.x;
  if (i < n4){
    float4 v = ((const float4*)in)[i];
    bf16x4 o = { (bf16_t)v.x, (bf16_t)v.y, (bf16_t)v.z, (bf16_t)v.w };
    ((bf16x4*)out)[i] = o;
  }
}

// ---------------- LayerNorm over last dim (1024), one block per row ----------------
template<int OUTBF>
__global__ __launch_bounds__(256) void ln_kernel(const float* __restrict__ x,
    const float* __restrict__ g, const float* __restrict__ b,
    float* __restrict__ outf, bf16_t* __restrict__ outb)
{
  int row = blockIdx.x;
  float4 v = ((const float4*)(x + (size_t)row*DMODEL))[threadIdx.x];
  float s  = v.x+v.y+v.z+v.w;
  float s2 = v.x*v.x+v.y*v.y+v.z*v.z+v.w*v.w;
  #pragma unroll
  for (int off=32; off>=1; off>>=1){ s += __shfl_xor(s,off); s2 += __shfl_xor(s2,off); }
  __shared__ float red[8];
  int lane = threadIdx.x & 63, wid = threadIdx.x >> 6;
  if (lane==0){ red[wid]=s; red[4+wid]=s2; }
  __syncthreads();
  float ts  = red[0]+red[1]+red[2]+red[3];
  float ts2 = red[4]+red[5]+red[6]+red[7];
  float mean = ts*(1.f/DMODEL);
  float var  = ts2*(1.f/DMODEL) - mean*mean;
  float rstd = rsqrtf(var + 1e-5f);
  float4 gv = ((const float4*)g)[threadIdx.x];
  float4 bv = ((const float4*)b)[threadIdx.x];
  float4 o;
  o.x=(v.x-mean)*rstd*gv.x+bv.x;
  o.y=(v.y-mean)*rstd*gv.y+bv.y;
  o.z=(v.z-mean)*rstd*gv.z+bv.z;
  o.w=(v.w-mean)*rstd*gv.w+bv.w;
  if (OUTBF){
    bf16x4 ob = { (bf16_t)o.x, (bf16_t)o.y, (bf16_t)o.z, (bf16_t)o.w };
    ((bf16x4*)(outb + (size_t)row*DMODEL))[threadIdx.x] = ob;
  } else {
    ((float4*)(outf + (size_t)row*DMODEL))[threadIdx.x] = o;
  }
}

// ================= bf16 MFMA GEMM: C[M,N] = A[M,K] * W[N,K]^T =================
#define GBM 128
#define GBN 128
#define GBK 64

template<int EPI, bool NGUARD, bool SWZ>
__global__ __launch_bounds__(256) void gemm_bf16(
    const bf16_t* __restrict__ A, int lda,
    const bf16_t* __restrict__ W, int ldw,
    float* __restrict__ C, int ldc,
    int M, int N, int K,
    const float* __restrict__ bias,
    const float* __restrict__ addsrc,
    bf16_t* __restrict__ C2)
{
  __shared__ __align__(16) char lds[2*GBM*GBK*2];   // 32 KB: sA | sB
  char* sA = lds;
  char* sB = lds + GBM*GBK*2;
  const int tid  = threadIdx.x;
  const int lane = tid & 63, wid = tid >> 6;
  const int wr = wid >> 1, wc = wid & 1;            // 2x2 wave grid
  const int frow = lane & 15, kgrp = lane >> 4;

  int bx = blockIdx.x, by = blockIdx.y;
  if (SWZ) {
    int gx = gridDim.x, gy = gridDim.y;
    int bid = by*gx + bx;
    int q = (gx*gy) >> 3;
    int nid = (bid & 7)*q + (bid >> 3);
    int stripH = gy << 3;
    int strip = nid / stripH;
    int rem   = nid % stripH;
    bx = (strip << 3) + (rem & 7);
    by = rem >> 3;
  }
  const int m0 = by*GBM, n0 = bx*GBN;
  const int srow  = (lane >> 3);          // 0..7 row within chunk
  const int scolb = (lane & 7) * 16;      // byte offset in K (0..112)

  f32x4 acc[4][4];
  #pragma unroll
  for (int i=0;i<4;i++)
    #pragma unroll
    for (int j=0;j<4;j++)
      acc[i][j] = (f32x4){0.f,0.f,0.f,0.f};

  const int ksl = K / gridDim.z;
  const int kb  = blockIdx.z * ksl;
  for (int k0 = kb; k0 < kb + ksl; k0 += GBK) {
    #pragma unroll
    for (int r=0;r<4;++r){
      int ci  = r*4 + wid;                // 0..15
      int row = ci*8 + srow;              // 0..127
      {
        const char* src = (const char*)A + ((size_t)(m0+row)*lda + k0)*2 + scolb;
        __builtin_amdgcn_global_load_lds(AS1(src), AS3(sA + ci*1024), 16, 0, 0);
      }
      {
        int grow = n0 + row;
        if (NGUARD) grow = (grow < N) ? grow : (N-1);
        const char* src = (const char*)W + ((size_t)grow*ldw + k0)*2 + scolb;
        __builtin_amdgcn_global_load_lds(AS1(src), AS3(sB + ci*1024), 16, 0, 0);
      }
    }
    __syncthreads();
    #pragma unroll
    for (int ks=0; ks<2; ++ks){
      bf16x8 af[4], bfr[4];
      #pragma unroll
      for (int i=0;i<4;i++)
        af[i] = *(const bf16x8*)(sA + (wr*64 + i*16 + frow)*128 + ks*64 + kgrp*16);
      #pragma unroll
      for (int j=0;j<4;j++)
        bfr[j] = *(const bf16x8*)(sB + (wc*64 + j*16 + frow)*128 + ks*64 + kgrp*16);
      #pragma unroll
      for (int i=0;i<4;i++)
        #pragma unroll
        for (int j=0;j<4;j++)
          acc[i][j] = __builtin_amdgcn_mfma_f32_16x16x32_bf16(af[i], bfr[j], acc[i][j], 0, 0, 0);
    }
    __syncthreads();
  }

  if (EPI==4) {
    #pragma unroll
    for (int i=0;i<4;i++){
      int rbase = wr*64 + i*16 + kgrp*4;
      #pragma unroll
      for (int j=0;j<4;j++){
        int col = wc*64 + j*16 + frow;
        #pragma unroll
        for (int q=0;q<4;q++){
          int row = rbase + q;
          int byte = (row<<8) + (col<<1);
          byte ^= (row & 7) << 4;
          *(bf16_t*)(lds + byte) = (bf16_t)acc[i][j][q];
        }
      }
    }
    __syncthreads();
    int r = tid >> 1;
    int hb = (tid & 1) << 7;              // byte offset 0/128 within row
    size_t gbase = (size_t)(m0 + r)*ldc + n0 + ((tid & 1) << 6);
    #pragma unroll
    for (int i=0;i<8;i++){
      int byte = (r<<8) + hb + (i<<4);
      byte ^= (r & 7) << 4;
      bf16x8 v = *(const bf16x8*)(lds + byte);
      *(bf16x8*)(C2 + gbase + (i<<3)) = v;
    }
    return;
  }

  float* Cw = (EPI==5) ? (C + (size_t)blockIdx.z*(size_t)M*ldc) : C;
  #pragma unroll
  for (int i=0;i<4;i++){
    int rbase = m0 + wr*64 + i*16 + kgrp*4;
    #pragma unroll
    for (int j=0;j<4;j++){
      int col = n0 + wc*64 + j*16 + frow;
      if (NGUARD && col >= N) continue;
      #pragma unroll
      for (int q=0;q<4;q++){
        float v = acc[i][j][q];
        int row = rbase + q;
        if (EPI==1) v = softplusf_(v + bias[col]);
        if (EPI==2) v += addsrc[(size_t)row*ldc + col];
        Cw[(size_t)row*ldc + col] = v;
      }
    }
  }
}

// ---------- x_proj split-K reduce ----------
__global__ __launch_bounds__(256) void xp_reduce(
    const float* __restrict__ part, float* __restrict__ xdbl, bf16_t* __restrict__ xdbl_b)
{
  int idx = blockIdx.x*256 + threadIdx.x;     // ROWS*96
  float s = 0.f;
  #pragma unroll
  for (int k=0;k<KSPLIT;k++) s += part[(size_t)k*ROWS*96 + idx];
  xdbl[idx] = s;
  xdbl_b[idx] = (bf16_t)s;
}

// ---------- causal depthwise conv (width 4) + bias + SiLU; bf16 in/out ----------
__global__ __launch_bounds__(256) void conv_silu_kernel(
    const bf16_t* __restrict__ xzb, const float* __restrict__ cw,
    const float* __restrict__ cb, bf16_t* __restrict__ ub)
{
  int idx = blockIdx.x*256 + threadIdx.x;     // B*L*DINNER threads
  int d  = idx & (DINNER-1);
  int bl = idx >> 11;
  int l  = bl & (LSEQ-1);
  const bf16_t* col = xzb + (size_t)bl*(2*DINNER) + d;
  float w0=cw[d*4+0], w1=cw[d*4+1], w2=cw[d*4+2], w3=cw[d*4+3];
  float x3 = (float)col[0];
  float x2 = (l>=1) ? (float)col[-(ptrdiff_t)(2*DINNER)]  : 0.f;
  float x1 = (l>=2) ? (float)col[-(ptrdiff_t)(4*DINNER)]  : 0.f;
  float x0 = (l>=3) ? (float)col[-(ptrdiff_t)(6*DINNER)]  : 0.f;
  float acc = cb[d] + w0*x0 + w1*x1 + w2*x2 + w3*x3;
  float uu = acc * sigmoidf_(acc);
  ub[(size_t)bl*DINNER + d] = (bf16_t)uu;
}

// ======================= chunked selective scan =======================
// Block = 256 threads, all same (b, chunk) -> B/C rows staged once in LDS.

// Phase 1: local scan h0=0 -> hout[b][c][d][16], sumd[b][c][d]
__global__ __launch_bounds__(256) void scan_phase1(
    const float* __restrict__ delta, const bf16_t* __restrict__ u,
    const float* __restrict__ xdbl, const float* __restrict__ A_log,
    float* __restrict__ hout, float* __restrict__ sumd)
{
  __shared__ __align__(16) float bcs[LCH][32];
  int tid = threadIdx.x;
  int gid = blockIdx.x*256 + tid;             // B*NCH*DINNER = 262144
  int d = gid & (DINNER-1);
  int c = (gid >> 11) & (NCH-1);
  int b = gid >> 17;
  int l0 = c*LCH;
  #pragma unroll
  for (int i=0;i<2;i++){
    int ii = tid + i*256;                     // 0..511
    int r = ii >> 5, q = ii & 31;
    bcs[r][q] = xdbl[(size_t)(b*LSEQ + l0 + r)*96 + DTRANK + q];
  }
  __syncthreads();

  f32x4 A4[4];
  #pragma unroll
  for (int si=0;si<4;si++){
    float4 al = ((const float4*)(A_log + d*DSTATE))[si];
    A4[si] = (f32x4){-__expf(al.x), -__expf(al.y), -__expf(al.z), -__expf(al.w)};
  }
  const float*  drow = delta + ((size_t)(b*LSEQ + l0))*DINNER + d;
  const bf16_t* urow = u     + ((size_t)(b*LSEQ + l0))*DINNER + d;
  f32x4 h[4] = {};
  float sd = 0.f;
  for (int l=0; l<LCH; ++l) {
    float dv = drow[(size_t)l*DINNER];
    float uv = (float)urow[(size_t)l*DINNER];
    float du = dv*uv;
    sd += dv;
    const f32x4* bl = (const f32x4*)&bcs[l][0];
    #pragma unroll
    for (int si=0;si<4;si++){
      f32x4 e;
      e[0]=__expf(dv*A4[si][0]); e[1]=__expf(dv*A4[si][1]);
      e[2]=__expf(dv*A4[si][2]); e[3]=__expf(dv*A4[si][3]);
      h[si] = e*h[si] + du*bl[si];
    }
  }
  float* hp = hout + (((size_t)(b*NCH + c))*DINNER + d)*DSTATE;
  #pragma unroll
  for (int si=0;si<4;si++) ((f32x4*)hp)[si] = h[si];
  sumd[((size_t)(b*NCH + c))*DINNER + d] = sd;
}

// Phase 2: per (b,d,s) compose over chunks; hout overwritten in place with hin
__global__ __launch_bounds__(256) void scan_phase2(
    float* __restrict__ hout, const float* __restrict__ sumd,
    const float* __restrict__ A_log)
{
  int gid = blockIdx.x*256 + threadIdx.x;     // B*DINNER*DSTATE = 65536
  int s = gid & (DSTATE-1);
  int d = (gid >> 4) & (DINNER-1);
  int b = gid >> 15;
  float A = -__expf(A_log[d*DSTATE+s]);
  float h = 0.f;
  for (int c=0; c<NCH; ++c) {
    size_t hi = (((size_t)(b*NCH + c))*DINNER + d)*DSTATE + s;
    float tmp = hout[hi];
    hout[hi] = h;                              // hin for chunk c
    float P = __expf(A * sumd[((size_t)(b*NCH + c))*DINNER + d]);
    h = P*h + tmp;
  }
}

// Phase 3: rescan with hin; fused epilogue; ys (bf16) overwrites u in place.
// ysb and u intentionally alias -> no __restrict__ on either.
__global__ __launch_bounds__(256) void scan_phase3(
    const float* __restrict__ delta, bf16_t* ysb,
    const bf16_t* u,
    const bf16_t* __restrict__ xzb,   // res at [row][2048+d], stride 4096
    const float* __restrict__ xdbl,   // [row][96]
    const float* __restrict__ A_log,
    const float* __restrict__ Dp,
    const float* __restrict__ hin)
{
  __shared__ __align__(16) float bcs[LCH][32];
  int tid = threadIdx.x;
  int gid = blockIdx.x*256 + tid;             // B*NCH*DINNER
  int d = gid & (DINNER-1);
  int c = (gid >> 11) & (NCH-1);
  int b = gid >> 17;
  int l0 = c*LCH;
  #pragma unroll
  for (int i=0;i<2;i++){
    int ii = tid + i*256;
    int r = ii >> 5, q = ii & 31;
    bcs[r][q] = xdbl[(size_t)(b*LSEQ + l0 + r)*96 + DTRANK + q];
  }
  __syncthreads();

  f32x4 A4[4];
  #pragma unroll
  for (int si=0;si<4;si++){
    float4 al = ((const float4*)(A_log + d*DSTATE))[si];
    A4[si] = (f32x4){-__expf(al.x), -__expf(al.y), -__expf(al.z), -__expf(al.w)};
  }
  float Dpd = Dp[d];
  f32x4 h[4];
  const float* hp = hin + (((size_t)(b*NCH + c))*DINNER + d)*DSTATE;
  #pragma unroll
  for (int si=0;si<4;si++) h[si] = ((const f32x4*)hp)[si];

  const float*  drow = delta + ((size_t)(b*LSEQ + l0))*DINNER + d;
  const bf16_t* urow = u     + ((size_t)(b*LSEQ + l0))*DINNER + d;
  const bf16_t* rrow = xzb   + ((size_t)(b*LSEQ + l0))*2*DINNER + DINNER + d;
  bf16_t* yrow = ysb + ((size_t)(b*LSEQ + l0))*DINNER + d;
  for (int l=0; l<LCH; ++l) {
    float dv = drow[(size_t)l*DINNER];
    float uv = (float)urow[(size_t)l*DINNER];
    float rv = (float)rrow[(size_t)l*2*DINNER];
    float du = dv*uv;
    const f32x4* bl = (const f32x4*)&bcs[l][0];
    f32x4 yv = {};
    #pragma unroll
    for (int si=0;si<4;si++){
      f32x4 e;
      e[0]=__expf(dv*A4[si][0]); e[1]=__expf(dv*A4[si][1]);
      e[2]=__expf(dv*A4[si][2]); e[3]=__expf(dv*A4[si][3]);
      h[si] = e*h[si] + du*bl[si];
      yv += h[si]*bl[4+si];
    }
    float y = yv[0]+yv[1]+yv[2]+yv[3];
    y = (y + uv*Dpd) * (rv * sigmoidf_(rv));
    yrow[(size_t)l*DINNER] = (bf16_t)y;
  }
}

extern "C" void kernel_launch(void* const* d_in, const int* in_sizes, int n_in,
                              void* d_out, int out_size, void* d_ws, size_t ws_size,
                              hipStream_t stream)
{
  const float* x      = (const float*)d_in[0];
  const float* ln_g   = (const float*)d_in[1];
  const float* ln_b   = (const float*)d_in[2];
  const float* in_w   = (const float*)d_in[3];
  const float* conv_w = (const float*)d_in[4];
  const float* conv_b = (const float*)d_in[5];
  const float* xp_w   = (const float*)d_in[6];
  const float* dt_w   = (const float*)d_in[7];
  const float* dt_b   = (const float*)d_in[8];
  const float* A_log  = (const float*)d_in[9];
  const float* Dp     = (const float*)d_in[10];
  const float* out_w  = (const float*)d_in[11];
  const float* fn_g   = (const float*)d_in[12];
  const float* fn_b   = (const float*)d_in[13];
  float* out = (float*)d_out;

  char* p = (char*)d_ws;
  auto alloc = [&](size_t bytes)->char*{ char* r = p; p += (bytes + 255) & ~(size_t)255; return r; };

  const size_t N_INW = (size_t)2*2*DINNER*DMODEL;
  const size_t N_XPW = (size_t)2*96*DINNER;
  const size_t N_DTW = (size_t)2*DINNER*DTRANK;
  const size_t N_OUTW= (size_t)2*DMODEL*DINNER;

  bf16_t* inw_b  = (bf16_t*)alloc(N_INW*2);
  bf16_t* xpw_b  = (bf16_t*)alloc(N_XPW*2);
  bf16_t* dtw_b  = (bf16_t*)alloc(N_DTW*2);
  bf16_t* outw_b = (bf16_t*)alloc(N_OUTW*2);
  float*  x_cur  = (float*) alloc((size_t)ROWS*DMODEL*4);
  bf16_t* xn_b   = (bf16_t*)alloc((size_t)ROWS*DMODEL*2);
  bf16_t* xzb    = (bf16_t*)alloc((size_t)ROWS*2*DINNER*2);
  bf16_t* ub_b   = (bf16_t*)alloc((size_t)ROWS*DINNER*2);     // u, later ys
  float*  xdbl   = (float*) alloc((size_t)ROWS*96*4);
  bf16_t* xdbl_b = (bf16_t*)alloc((size_t)ROWS*96*2);
  float*  xpart  = (float*) alloc((size_t)KSPLIT*ROWS*96*4);
  float*  delta  = (float*) alloc((size_t)ROWS*DINNER*4);
  float*  hout   = (float*) alloc((size_t)NB*NCH*DINNER*DSTATE*4); // 16.8 MB
  float*  sumd   = (float*) alloc((size_t)NB*NCH*DINNER*4);
  bf16_t* ys_b   = ub_b;

  cvt_kernel<<<(int)((N_INW/4 +255)/256),256,0,stream>>>(in_w,  inw_b,  (int)(N_INW/4));
  cvt_kernel<<<(int)((N_XPW/4 +255)/256),256,0,stream>>>(xp_w,  xpw_b,  (int)(N_XPW/4));
  cvt_kernel<<<(int)((N_DTW/4 +255)/256),256,0,stream>>>(dt_w,  dtw_b,  (int)(N_DTW/4));
  cvt_kernel<<<(int)((N_OUTW/4+255)/256),256,0,stream>>>(out_w, outw_b, (int)(N_OUTW/4));

  for (int layer=0; layer<2; ++layer) {
    const float* xin = (layer==0) ? x : x_cur;
    const float* Al  = A_log + (size_t)layer*DINNER*DSTATE;
    ln_kernel<1><<<ROWS,256,0,stream>>>(xin, ln_g+layer*DMODEL, ln_b+layer*DMODEL, nullptr, xn_b);
    // xz = xn @ in_w^T   [2048 x 4096], K=1024  -> bf16 out
    gemm_bf16<4,false,true><<<dim3(2*DINNER/GBN, ROWS/GBM),256,0,stream>>>(
        xn_b, DMODEL, inw_b + (size_t)layer*2*DINNER*DMODEL, DMODEL,
        nullptr, 2*DINNER, ROWS, 2*DINNER, DMODEL, nullptr, nullptr, xzb);
    // u = silu(conv(xz[:, :2048]) + cb)
    conv_silu_kernel<<<(ROWS*DINNER)/256,256,0,stream>>>(
        xzb, conv_w + (size_t)layer*DINNER*4, conv_b + (size_t)layer*DINNER, ub_b);
    // xdbl = u @ xp_w^T  split-K
    gemm_bf16<5,true,false><<<dim3(1, ROWS/GBM, KSPLIT),256,0,stream>>>(
        ub_b, DINNER, xpw_b + (size_t)layer*96*DINNER, DINNER,
        xpart, 96, ROWS, 96, DINNER, nullptr, nullptr, nullptr);
    xp_reduce<<<(ROWS*96)/256,256,0,stream>>>(xpart, xdbl, xdbl_b);
    // delta = softplus(xdbl[:, :64] @ dt_w^T + dt_b)
    gemm_bf16<1,false,true><<<dim3(DINNER/GBN, ROWS/GBM),256,0,stream>>>(
        xdbl_b, 96, dtw_b + (size_t)layer*DINNER*DTRANK, DTRANK,
        delta, DINNER, ROWS, DINNER, DTRANK,
        dt_b + (size_t)layer*DINNER, nullptr, nullptr);
    // chunked selective scan (ys bf16 in place over u)
    scan_phase1<<<(NB*NCH*DINNER)/256,256,0,stream>>>(delta, ub_b, xdbl, Al, hout, sumd);
    scan_phase2<<<(NB*DINNER*DSTATE)/256,256,0,stream>>>(hout, sumd, Al);
    scan_phase3<<<(NB*NCH*DINNER)/256,256,0,stream>>>(
        delta, ys_b, ub_b, xzb, xdbl, Al, Dp + (size_t)layer*DINNER, hout);
    // x_cur = xin + ys @ out_w^T
    gemm_bf16<2,false,true><<<dim3(DMODEL/GBN, ROWS/GBM),256,0,stream>>>(
        ys_b, DINNER, outw_b + (size_t)layer*DMODEL*DINNER, DINNER,
        x_cur, DMODEL, ROWS, DMODEL, DINNER, nullptr, xin, nullptr);
  }
  ln_kernel<0><<<ROWS,256,0,stream>>>(x_cur, fn_g, fn_b, out, nullptr);
}

// Round 8
// 445.467 us; speedup vs baseline: 1.2288x; 1.0780x over previous
//
#include <hip/hip_runtime.h>
#include <hip/hip_bf16.h>
#include <math.h>
#include <stdint.h>

#define DMODEL 1024
#define DSTATE 16
#define DINNER 2048
#define DTRANK 64
#define NB 2
#define LSEQ 1024
#define ROWS (NB*LSEQ)   // 2048
#define NCH 64           // chunks per sequence
#define LCH (LSEQ/NCH)   // 16 steps per chunk
#define KSPLIT 8         // x_proj split-K factor

typedef __bf16 bf16_t;
typedef __bf16 bf16x8 __attribute__((ext_vector_type(8)));
typedef __bf16 bf16x4 __attribute__((ext_vector_type(4)));
typedef float  f32x4  __attribute__((ext_vector_type(4)));

#define AS1(p) ((const __attribute__((address_space(1))) void*)(p))
#define AS3(p) ((__attribute__((address_space(3))) void*)(uint32_t)(uintptr_t)(p))

static __device__ __forceinline__ float sigmoidf_(float x){ return 1.f/(1.f+__expf(-x)); }
static __device__ __forceinline__ float softplusf_(float x){ return fmaxf(x,0.f) + log1pf(__expf(-fabsf(x))); }

// ---------------- f32 -> bf16 conversion (weights) ----------------
__global__ __launch_bounds__(256) void cvt_kernel(const float* __restrict__ in,
    bf16_t* __restrict__ out, int n4)
{
  int i = blockIdx.x*256 + threadIdx.x;
  if (i < n4){
    float4 v = ((const float4*)in)[i];
    bf16x4 o = { (bf16_t)v.x, (bf16_t)v.y, (bf16_t)v.z, (bf16_t)v.w };
    ((bf16x4*)out)[i] = o;
  }
}

// ---------------- LayerNorm over last dim (1024), one block per row ----------------
template<int OUTBF>
__global__ __launch_bounds__(256) void ln_kernel(const float* __restrict__ x,
    const float* __restrict__ g, const float* __restrict__ b,
    float* __restrict__ outf, bf16_t* __restrict__ outb)
{
  int row = blockIdx.x;
  float4 v = ((const float4*)(x + (size_t)row*DMODEL))[threadIdx.x];
  float s  = v.x+v.y+v.z+v.w;
  float s2 = v.x*v.x+v.y*v.y+v.z*v.z+v.w*v.w;
  #pragma unroll
  for (int off=32; off>=1; off>>=1){ s += __shfl_xor(s,off); s2 += __shfl_xor(s2,off); }
  __shared__ float red[8];
  int lane = threadIdx.x & 63, wid = threadIdx.x >> 6;
  if (lane==0){ red[wid]=s; red[4+wid]=s2; }
  __syncthreads();
  float ts  = red[0]+red[1]+red[2]+red[3];
  float ts2 = red[4]+red[5]+red[6]+red[7];
  float mean = ts*(1.f/DMODEL);
  float var  = ts2*(1.f/DMODEL) - mean*mean;
  float rstd = rsqrtf(var + 1e-5f);
  float4 gv = ((const float4*)g)[threadIdx.x];
  float4 bv = ((const float4*)b)[threadIdx.x];
  float4 o;
  o.x=(v.x-mean)*rstd*gv.x+bv.x;
  o.y=(v.y-mean)*rstd*gv.y+bv.y;
  o.z=(v.z-mean)*rstd*gv.z+bv.z;
  o.w=(v.w-mean)*rstd*gv.w+bv.w;
  if (OUTBF){
    bf16x4 ob = { (bf16_t)o.x, (bf16_t)o.y, (bf16_t)o.z, (bf16_t)o.w };
    ((bf16x4*)(outb + (size_t)row*DMODEL))[threadIdx.x] = ob;
  } else {
    ((float4*)(outf + (size_t)row*DMODEL))[threadIdx.x] = o;
  }
}

// ================= bf16 MFMA GEMM: C[M,N] = A[M,K] * W[N,K]^T =================
// 128x128 tile, BK=64, 4 waves (2x2). 2-phase double-buffered LDS pipeline:
// issue global_load_lds for tile t+1 into idle buffer, compute tile t, ONE
// barrier per K-step (its vmcnt(0) drain lands after the compute phase).
#define GBM 128
#define GBN 128
#define GBK 64

template<int EPI, bool NGUARD, bool SWZ>
__global__ __launch_bounds__(256) void gemm_bf16(
    const bf16_t* __restrict__ A, int lda,
    const bf16_t* __restrict__ W, int ldw,
    float* __restrict__ C, int ldc,
    int M, int N, int K,
    const float* __restrict__ bias,
    const float* __restrict__ addsrc,
    bf16_t* __restrict__ C2)
{
  __shared__ __align__(16) char lds[65536];   // 2 buffers x (sA 16K | sB 16K)
  const int tid  = threadIdx.x;
  const int lane = tid & 63, wid = tid >> 6;
  const int wr = wid >> 1, wc = wid & 1;            // 2x2 wave grid
  const int frow = lane & 15, kgrp = lane >> 4;

  int bx = blockIdx.x, by = blockIdx.y;
  if (SWZ) {
    int gx = gridDim.x, gy = gridDim.y;
    int bid = by*gx + bx;
    int q = (gx*gy) >> 3;
    int nid = (bid & 7)*q + (bid >> 3);
    int stripH = gy << 3;
    int strip = nid / stripH;
    int rem   = nid % stripH;
    bx = (strip << 3) + (rem & 7);
    by = rem >> 3;
  }
  const int m0 = by*GBM, n0 = bx*GBN;
  const int srow  = (lane >> 3);          // 0..7 row within chunk
  const int scolb = (lane & 7) * 16;      // byte offset in K (0..112)

  f32x4 acc[4][4];
  #pragma unroll
  for (int i=0;i<4;i++)
    #pragma unroll
    for (int j=0;j<4;j++)
      acc[i][j] = (f32x4){0.f,0.f,0.f,0.f};

  auto STAGE = [&](int k0, char* sAb, char* sBb){
    #pragma unroll
    for (int r=0;r<4;++r){
      int ci  = r*4 + wid;                // 0..15
      int row = ci*8 + srow;              // 0..127
      {
        const char* src = (const char*)A + ((size_t)(m0+row)*lda + k0)*2 + scolb;
        __builtin_amdgcn_global_load_lds(AS1(src), AS3(sAb + ci*1024), 16, 0, 0);
      }
      {
        int grow = n0 + row;
        if (NGUARD) grow = (grow < N) ? grow : (N-1);
        const char* src = (const char*)W + ((size_t)grow*ldw + k0)*2 + scolb;
        __builtin_amdgcn_global_load_lds(AS1(src), AS3(sBb + ci*1024), 16, 0, 0);
      }
    }
  };

  const int ksl = K / gridDim.z;
  const int kb  = blockIdx.z * ksl;
  const int nt  = ksl / GBK;

  STAGE(kb, lds, lds + 16384);
  __syncthreads();                        // buf0 ready
  int cur = 0;
  for (int t = 0; t < nt; ++t) {
    char* cA = lds + cur*32768;
    char* cB = cA + 16384;
    if (t+1 < nt) {
      char* nA = lds + (cur^1)*32768;
      STAGE(kb + (t+1)*GBK, nA, nA + 16384);   // loads fly during compute below
    }
    #pragma unroll
    for (int ks=0; ks<2; ++ks){
      bf16x8 af[4], bfr[4];
      #pragma unroll
      for (int i=0;i<4;i++)
        af[i] = *(const bf16x8*)(cA + (wr*64 + i*16 + frow)*128 + ks*64 + kgrp*16);
      #pragma unroll
      for (int j=0;j<4;j++)
        bfr[j] = *(const bf16x8*)(cB + (wc*64 + j*16 + frow)*128 + ks*64 + kgrp*16);
      #pragma unroll
      for (int i=0;i<4;i++)
        #pragma unroll
        for (int j=0;j<4;j++)
          acc[i][j] = __builtin_amdgcn_mfma_f32_16x16x32_bf16(af[i], bfr[j], acc[i][j], 0, 0, 0);
    }
    __syncthreads();   // drains next-tile loads; all waves done reading cur
    cur ^= 1;
  }

  if (EPI==4) {
    // stage C tile to LDS as bf16 (XOR-swizzled), then coalesced 16B stores
    #pragma unroll
    for (int i=0;i<4;i++){
      int rbase = wr*64 + i*16 + kgrp*4;
      #pragma unroll
      for (int j=0;j<4;j++){
        int col = wc*64 + j*16 + frow;
        #pragma unroll
        for (int q=0;q<4;q++){
          int row = rbase + q;
          int byte = (row<<8) + (col<<1);
          byte ^= (row & 7) << 4;
          *(bf16_t*)(lds + byte) = (bf16_t)acc[i][j][q];
        }
      }
    }
    __syncthreads();
    int r = tid >> 1;
    int hb = (tid & 1) << 7;              // byte offset 0/128 within row
    size_t gbase = (size_t)(m0 + r)*ldc + n0 + ((tid & 1) << 6);
    #pragma unroll
    for (int i=0;i<8;i++){
      int byte = (r<<8) + hb + (i<<4);
      byte ^= (r & 7) << 4;
      bf16x8 v = *(const bf16x8*)(lds + byte);
      *(bf16x8*)(C2 + gbase + (i<<3)) = v;
    }
    return;
  }

  float* Cw = (EPI==5) ? (C + (size_t)blockIdx.z*(size_t)M*ldc) : C;
  #pragma unroll
  for (int i=0;i<4;i++){
    int rbase = m0 + wr*64 + i*16 + kgrp*4;
    #pragma unroll
    for (int j=0;j<4;j++){
      int col = n0 + wc*64 + j*16 + frow;
      if (NGUARD && col >= N) continue;
      #pragma unroll
      for (int q=0;q<4;q++){
        float v = acc[i][j][q];
        int row = rbase + q;
        if (EPI==1) v = softplusf_(v + bias[col]);
        if (EPI==2) v += addsrc[(size_t)row*ldc + col];
        Cw[(size_t)row*ldc + col] = v;
      }
    }
  }
}

// ---------- x_proj split-K reduce ----------
__global__ __launch_bounds__(256) void xp_reduce(
    const float* __restrict__ part, float* __restrict__ xdbl, bf16_t* __restrict__ xdbl_b)
{
  int idx = blockIdx.x*256 + threadIdx.x;     // ROWS*96
  float s = 0.f;
  #pragma unroll
  for (int k=0;k<KSPLIT;k++) s += part[(size_t)k*ROWS*96 + idx];
  xdbl[idx] = s;
  xdbl_b[idx] = (bf16_t)s;
}

// ---------- causal depthwise conv (width 4) + bias + SiLU; bf16 in/out ----------
__global__ __launch_bounds__(256) void conv_silu_kernel(
    const bf16_t* __restrict__ xzb, const float* __restrict__ cw,
    const float* __restrict__ cb, bf16_t* __restrict__ ub)
{
  int idx = blockIdx.x*256 + threadIdx.x;     // B*L*DINNER threads
  int d  = idx & (DINNER-1);
  int bl = idx >> 11;
  int l  = bl & (LSEQ-1);
  const bf16_t* col = xzb + (size_t)bl*(2*DINNER) + d;
  float w0=cw[d*4+0], w1=cw[d*4+1], w2=cw[d*4+2], w3=cw[d*4+3];
  float x3 = (float)col[0];
  float x2 = (l>=1) ? (float)col[-(ptrdiff_t)(2*DINNER)]  : 0.f;
  float x1 = (l>=2) ? (float)col[-(ptrdiff_t)(4*DINNER)]  : 0.f;
  float x0 = (l>=3) ? (float)col[-(ptrdiff_t)(6*DINNER)]  : 0.f;
  float acc = cb[d] + w0*x0 + w1*x1 + w2*x2 + w3*x3;
  float uu = acc * sigmoidf_(acc);
  ub[(size_t)bl*DINNER + d] = (bf16_t)uu;
}

// ======================= chunked selective scan =======================
// Block = 256 threads, all same (b, chunk) -> B/C rows staged once in LDS.

// Phase 1: local scan h0=0 -> hout[b][c][d][16], sumd[b][c][d]
__global__ __launch_bounds__(256) void scan_phase1(
    const float* __restrict__ delta, const bf16_t* __restrict__ u,
    const float* __restrict__ xdbl, const float* __restrict__ A_log,
    float* __restrict__ hout, float* __restrict__ sumd)
{
  __shared__ __align__(16) float bcs[LCH][32];
  int tid = threadIdx.x;
  int gid = blockIdx.x*256 + tid;             // B*NCH*DINNER = 262144
  int d = gid & (DINNER-1);
  int c = (gid >> 11) & (NCH-1);
  int b = gid >> 17;
  int l0 = c*LCH;
  #pragma unroll
  for (int i=0;i<2;i++){
    int ii = tid + i*256;                     // 0..511
    int r = ii >> 5, q = ii & 31;
    bcs[r][q] = xdbl[(size_t)(b*LSEQ + l0 + r)*96 + DTRANK + q];
  }
  __syncthreads();

  f32x4 A4[4];
  #pragma unroll
  for (int si=0;si<4;si++){
    float4 al = ((const float4*)(A_log + d*DSTATE))[si];
    A4[si] = (f32x4){-__expf(al.x), -__expf(al.y), -__expf(al.z), -__expf(al.w)};
  }
  const float*  drow = delta + ((size_t)(b*LSEQ + l0))*DINNER + d;
  const bf16_t* urow = u     + ((size_t)(b*LSEQ + l0))*DINNER + d;
  f32x4 h[4] = {};
  float sd = 0.f;
  for (int l=0; l<LCH; ++l) {
    float dv = drow[(size_t)l*DINNER];
    float uv = (float)urow[(size_t)l*DINNER];
    float du = dv*uv;
    sd += dv;
    const f32x4* bl = (const f32x4*)&bcs[l][0];
    #pragma unroll
    for (int si=0;si<4;si++){
      f32x4 e;
      e[0]=__expf(dv*A4[si][0]); e[1]=__expf(dv*A4[si][1]);
      e[2]=__expf(dv*A4[si][2]); e[3]=__expf(dv*A4[si][3]);
      h[si] = e*h[si] + du*bl[si];
    }
  }
  float* hp = hout + (((size_t)(b*NCH + c))*DINNER + d)*DSTATE;
  #pragma unroll
  for (int si=0;si<4;si++) ((f32x4*)hp)[si] = h[si];
  sumd[((size_t)(b*NCH + c))*DINNER + d] = sd;
}

// Phase 2: per (b,d,s) compose over chunks; hout overwritten in place with hin
__global__ __launch_bounds__(256) void scan_phase2(
    float* __restrict__ hout, const float* __restrict__ sumd,
    const float* __restrict__ A_log)
{
  int gid = blockIdx.x*256 + threadIdx.x;     // B*DINNER*DSTATE = 65536
  int s = gid & (DSTATE-1);
  int d = (gid >> 4) & (DINNER-1);
  int b = gid >> 15;
  float A = -__expf(A_log[d*DSTATE+s]);
  float h = 0.f;
  for (int c=0; c<NCH; ++c) {
    size_t hi = (((size_t)(b*NCH + c))*DINNER + d)*DSTATE + s;
    float tmp = hout[hi];
    hout[hi] = h;                              // hin for chunk c
    float P = __expf(A * sumd[((size_t)(b*NCH + c))*DINNER + d]);
    h = P*h + tmp;
  }
}

// Phase 3: rescan with hin; fused epilogue; ys (bf16) overwrites u in place.
// ysb and u intentionally alias -> no __restrict__ on either.
__global__ __launch_bounds__(256) void scan_phase3(
    const float* __restrict__ delta, bf16_t* ysb,
    const bf16_t* u,
    const bf16_t* __restrict__ xzb,   // res at [row][2048+d], stride 4096
    const float* __restrict__ xdbl,   // [row][96]
    const float* __restrict__ A_log,
    const float* __restrict__ Dp,
    const float* __restrict__ hin)
{
  __shared__ __align__(16) float bcs[LCH][32];
  int tid = threadIdx.x;
  int gid = blockIdx.x*256 + tid;             // B*NCH*DINNER
  int d = gid & (DINNER-1);
  int c = (gid >> 11) & (NCH-1);
  int b = gid >> 17;
  int l0 = c*LCH;
  #pragma unroll
  for (int i=0;i<2;i++){
    int ii = tid + i*256;
    int r = ii >> 5, q = ii & 31;
    bcs[r][q] = xdbl[(size_t)(b*LSEQ + l0 + r)*96 + DTRANK + q];
  }
  __syncthreads();

  f32x4 A4[4];
  #pragma unroll
  for (int si=0;si<4;si++){
    float4 al = ((const float4*)(A_log + d*DSTATE))[si];
    A4[si] = (f32x4){-__expf(al.x), -__expf(al.y), -__expf(al.z), -__expf(al.w)};
  }
  float Dpd = Dp[d];
  f32x4 h[4];
  const float* hp = hin + (((size_t)(b*NCH + c))*DINNER + d)*DSTATE;
  #pragma unroll
  for (int si=0;si<4;si++) h[si] = ((const f32x4*)hp)[si];

  const float*  drow = delta + ((size_t)(b*LSEQ + l0))*DINNER + d;
  const bf16_t* urow = u     + ((size_t)(b*LSEQ + l0))*DINNER + d;
  const bf16_t* rrow = xzb   + ((size_t)(b*LSEQ + l0))*2*DINNER + DINNER + d;
  bf16_t* yrow = ysb + ((size_t)(b*LSEQ + l0))*DINNER + d;
  for (int l=0; l<LCH; ++l) {
    float dv = drow[(size_t)l*DINNER];
    float uv = (float)urow[(size_t)l*DINNER];
    float rv = (float)rrow[(size_t)l*2*DINNER];
    float du = dv*uv;
    const f32x4* bl = (const f32x4*)&bcs[l][0];
    f32x4 yv = {};
    #pragma unroll
    for (int si=0;si<4;si++){
      f32x4 e;
      e[0]=__expf(dv*A4[si][0]); e[1]=__expf(dv*A4[si][1]);
      e[2]=__expf(dv*A4[si][2]); e[3]=__expf(dv*A4[si][3]);
      h[si] = e*h[si] + du*bl[si];
      yv += h[si]*bl[4+si];
    }
    float y = yv[0]+yv[1]+yv[2]+yv[3];
    y = (y + uv*Dpd) * (rv * sigmoidf_(rv));
    yrow[(size_t)l*DINNER] = (bf16_t)y;
  }
}

extern "C" void kernel_launch(void* const* d_in, const int* in_sizes, int n_in,
                              void* d_out, int out_size, void* d_ws, size_t ws_size,
                              hipStream_t stream)
{
  const float* x      = (const float*)d_in[0];
  const float* ln_g   = (const float*)d_in[1];
  const float* ln_b   = (const float*)d_in[2];
  const float* in_w   = (const float*)d_in[3];
  const float* conv_w = (const float*)d_in[4];
  const float* conv_b = (const float*)d_in[5];
  const float* xp_w   = (const float*)d_in[6];
  const float* dt_w   = (const float*)d_in[7];
  const float* dt_b   = (const float*)d_in[8];
  const float* A_log  = (const float*)d_in[9];
  const float* Dp     = (const float*)d_in[10];
  const float* out_w  = (const float*)d_in[11];
  const float* fn_g   = (const float*)d_in[12];
  const float* fn_b   = (const float*)d_in[13];
  float* out = (float*)d_out;

  char* p = (char*)d_ws;
  auto alloc = [&](size_t bytes)->char*{ char* r = p; p += (bytes + 255) & ~(size_t)255; return r; };

  const size_t N_INW = (size_t)2*2*DINNER*DMODEL;
  const size_t N_XPW = (size_t)2*96*DINNER;
  const size_t N_DTW = (size_t)2*DINNER*DTRANK;
  const size_t N_OUTW= (size_t)2*DMODEL*DINNER;

  bf16_t* inw_b  = (bf16_t*)alloc(N_INW*2);
  bf16_t* xpw_b  = (bf16_t*)alloc(N_XPW*2);
  bf16_t* dtw_b  = (bf16_t*)alloc(N_DTW*2);
  bf16_t* outw_b = (bf16_t*)alloc(N_OUTW*2);
  float*  x_cur  = (float*) alloc((size_t)ROWS*DMODEL*4);
  bf16_t* xn_b   = (bf16_t*)alloc((size_t)ROWS*DMODEL*2);
  bf16_t* xzb    = (bf16_t*)alloc((size_t)ROWS*2*DINNER*2);
  bf16_t* ub_b   = (bf16_t*)alloc((size_t)ROWS*DINNER*2);     // u, later ys
  float*  xdbl   = (float*) alloc((size_t)ROWS*96*4);
  bf16_t* xdbl_b = (bf16_t*)alloc((size_t)ROWS*96*2);
  float*  xpart  = (float*) alloc((size_t)KSPLIT*ROWS*96*4);
  float*  delta  = (float*) alloc((size_t)ROWS*DINNER*4);
  float*  hout   = (float*) alloc((size_t)NB*NCH*DINNER*DSTATE*4); // 16.8 MB
  float*  sumd   = (float*) alloc((size_t)NB*NCH*DINNER*4);
  bf16_t* ys_b   = ub_b;

  cvt_kernel<<<(int)((N_INW/4 +255)/256),256,0,stream>>>(in_w,  inw_b,  (int)(N_INW/4));
  cvt_kernel<<<(int)((N_XPW/4 +255)/256),256,0,stream>>>(xp_w,  xpw_b,  (int)(N_XPW/4));
  cvt_kernel<<<(int)((N_DTW/4 +255)/256),256,0,stream>>>(dt_w,  dtw_b,  (int)(N_DTW/4));
  cvt_kernel<<<(int)((N_OUTW/4+255)/256),256,0,stream>>>(out_w, outw_b, (int)(N_OUTW/4));

  for (int layer=0; layer<2; ++layer) {
    const float* xin = (layer==0) ? x : x_cur;
    const float* Al  = A_log + (size_t)layer*DINNER*DSTATE;
    ln_kernel<1><<<ROWS,256,0,stream>>>(xin, ln_g+layer*DMODEL, ln_b+layer*DMODEL, nullptr, xn_b);
    // xz = xn @ in_w^T   [2048 x 4096], K=1024  -> bf16 out
    gemm_bf16<4,false,true><<<dim3(2*DINNER/GBN, ROWS/GBM),256,0,stream>>>(
        xn_b, DMODEL, inw_b + (size_t)layer*2*DINNER*DMODEL, DMODEL,
        nullptr, 2*DINNER, ROWS, 2*DINNER, DMODEL, nullptr, nullptr, xzb);
    // u = silu(conv(xz[:, :2048]) + cb)
    conv_silu_kernel<<<(ROWS*DINNER)/256,256,0,stream>>>(
        xzb, conv_w + (size_t)layer*DINNER*4, conv_b + (size_t)layer*DINNER, ub_b);
    // xdbl = u @ xp_w^T  split-K
    gemm_bf16<5,true,false><<<dim3(1, ROWS/GBM, KSPLIT),256,0,stream>>>(
        ub_b, DINNER, xpw_b + (size_t)layer*96*DINNER, DINNER,
        xpart, 96, ROWS, 96, DINNER, nullptr, nullptr, nullptr);
    xp_reduce<<<(ROWS*96)/256,256,0,stream>>>(xpart, xdbl, xdbl_b);
    // delta = softplus(xdbl[:, :64] @ dt_w^T + dt_b)
    gemm_bf16<1,false,true><<<dim3(DINNER/GBN, ROWS/GBM),256,0,stream>>>(
        xdbl_b, 96, dtw_b + (size_t)layer*DINNER*DTRANK, DTRANK,
        delta, DINNER, ROWS, DINNER, DTRANK,
        dt_b + (size_t)layer*DINNER, nullptr, nullptr);
    // chunked selective scan (ys bf16 in place over u)
    scan_phase1<<<(NB*NCH*DINNER)/256,256,0,stream>>>(delta, ub_b, xdbl, Al, hout, sumd);
    scan_phase2<<<(NB*DINNER*DSTATE)/256,256,0,stream>>>(hout, sumd, Al);
    scan_phase3<<<(NB*NCH*DINNER)/256,256,0,stream>>>(
        delta, ys_b, ub_b, xzb, xdbl, Al, Dp + (size_t)layer*DINNER, hout);
    // x_cur = xin + ys @ out_w^T
    gemm_bf16<2,false,true><<<dim3(DMODEL/GBN, ROWS/GBM),256,0,stream>>>(
        ys_b, DINNER, outw_b + (size_t)layer*DMODEL*DINNER, DINNER,
        x_cur, DMODEL, ROWS, DMODEL, DINNER, nullptr, xin, nullptr);
  }
  ln_kernel<0><<<ROWS,256,0,stream>>>(x_cur, fn_g, fn_b, out, nullptr);
}